// Round 8
// baseline (153.751 us; speedup 1.0000x reference)
//
#include <hip/hip_runtime.h>
#include <hip/hip_fp16.h>
#include <math.h>

#define BATCH 8
#define CH    64
#define HH    128
#define WW    128
#define HWSZ  (HH * WW)       // 16384
#define COUT  64
#define KTAPS 9
#define KDIM  576             // CH * KTAPS
#define LSTR  72              // ushorts per colL px-row (144 B)
#define WCOLS 68              // window cols: x0-2 .. x0+65
#define WPX   340             // 5 rows x 68 cols
#define WSEG  2720            // ushorts per ch-segment: 340 px * 8 ch

typedef __attribute__((ext_vector_type(8))) short short8;
typedef __attribute__((ext_vector_type(4))) float f32x4;
typedef __attribute__((ext_vector_type(2))) float f32x2;

__device__ __forceinline__ unsigned short f2bf(float f) {
    unsigned int u = __float_as_uint(f);
    u += 0x7fffu + ((u >> 16) & 1u);
    return (unsigned short)(u >> 16);
}
__device__ __forceinline__ f32x2 up2(unsigned int u) {
    f32x2 r;
    r.x = __uint_as_float(u << 16);
    r.y = __uint_as_float(u & 0xffff0000u);
    return r;
}
__device__ __forceinline__ unsigned int bilin2(unsigned int a, unsigned int b,
                                               unsigned int c, unsigned int d,
                                               float w00, float w01, float w10, float w11) {
    f32x2 acc = up2(a) * w00;
    acc = up2(b) * w01 + acc;
    acc = up2(c) * w10 + acc;
    acc = up2(d) * w11 + acc;
    return __builtin_amdgcn_perm(__float_as_uint(acc.y) + 0x8000u,
                                 __float_as_uint(acc.x) + 0x8000u, 0x07060302u);
}

// ---------------------------------------------------------------------------
// Kernel 0: NCHW fp32 -> NHWC bf16 transpose; blocks < 216 also repack conv
// weights into wave-contiguous A-fragment layouts (1 KB = 8 full lines/instr).
// ---------------------------------------------------------------------------
__global__ __launch_bounds__(256) void transpose_x_kernel(
    const float* __restrict__ x, unsigned short* __restrict__ xt,
    const float* __restrict__ w_dcn, const float* __restrict__ w_off,
    unsigned short* __restrict__ wpk, unsigned short* __restrict__ wopk) {
    __shared__ unsigned short t[64 * LSTR];
    int tid = threadIdx.x, bid = blockIdx.x;

    if (bid < 216) {  // 216*256 = 55296 = 36864 + 18432
        int j = bid * 256 + tid;
        if (j < 36864) {
            int jj = j & 7, ln = (j >> 3) & 63, q = j >> 9;   // q: 0..71
            int ks = q % 18, mt = q / 18;
            int tap = ks >> 1, h = ks & 1;
            int co = mt * 16 + (ln & 15);
            int c  = h * 32 + (ln >> 4) * 8 + jj;
            wpk[j] = f2bf(w_dcn[(co * CH + c) * KTAPS + tap]);
        } else {
            int jo = j - 36864;
            int jj = jo & 7, ln = (jo >> 3) & 63, q = jo >> 9; // q: 0..35
            int ks = q % 18, cot = q / 18;
            int tap = ks >> 1, h = ks & 1;
            int co = cot * 16 + (ln & 15);
            int c  = h * 32 + (ln >> 4) * 8 + jj;
            wopk[jo] = (co < 27) ? f2bf(w_off[(co * CH + c) * KTAPS + tap]) : 0;
        }
    }

    int b = bid >> 8;
    int pxbase = (bid & 255) * 64;
    int lane = tid & 63, wv = tid >> 6;
    const float* xb = x + (size_t)b * CH * HWSZ + pxbase;
#pragma unroll
    for (int i = 0; i < 16; ++i) {
        int c = wv * 16 + i;
        t[lane * LSTR + c] = f2bf(xb[(size_t)c * HWSZ + lane]);
    }
    __syncthreads();
    int px = tid >> 2, cp = (tid & 3) * 16;
    uint4 q0 = *(const uint4*)&t[px * LSTR + cp];
    uint4 q1 = *(const uint4*)&t[px * LSTR + cp + 8];
    unsigned short* o = xt + (size_t)(b * HWSZ + pxbase + px) * 64 + cp;
    *(uint4*)o = q0;
    *(uint4*)(o + 8) = q1;
}

// ---------------------------------------------------------------------------
// Kernel 1: FUSED DCN with LDS x-window.
//  Stage: win[c8][340px][8ch] <- 5x68 px neighborhood (OOB image px = 0).
//  Phase 1: offset GEMM 32co x 64px, B-frags ds_read from window (no barriers)
//  Phase 2: bilinear params -> wgt (2x half2) + idx (window slots | bit15 ->
//           global fallback through xt, any-offset correctness).
//  Phase 3: per tap: col build (corners from window) -> colL -> MFMA 64co x 64px.
// LDS: win 43520 | colL 9216 (union omr 6912) | wgt 4608 | idx 4608 = 61952 B
// ---------------------------------------------------------------------------
__global__ __launch_bounds__(256) void dcn_fused_mfma(
    const unsigned short* __restrict__ xt, const unsigned short* __restrict__ wpk,
    const unsigned short* __restrict__ wopk, const float* __restrict__ b_off,
    const float* __restrict__ b_dcn, float* __restrict__ out) {
    __shared__ __align__(16) unsigned char smem[61952];
    unsigned short* win = (unsigned short*)smem;           // [8][WSEG]
    unsigned short* colL = (unsigned short*)(smem + 43520);
    float* omr = (float*)(smem + 43520);                   // union w/ colL
    uint2* wgt = (uint2*)(smem + 52736);                   // [9][64] {h2,h2}
    ushort4* idxA = (ushort4*)(smem + 57344);              // [9][64]

    int tid = threadIdx.x, bid = blockIdx.x;
    int b = bid & 7;                 // batch -> XCD pinning
    int pxbase = (bid >> 3) * 64;
    int y = pxbase >> 7;             // tile row
    int x0 = pxbase & (WW - 1);      // tile col base (0 or 64)
    int lane = tid & 63, wv = tid >> 6;
    int quad = lane >> 4, n16 = lane & 15;
    int h8 = lane & 7, p8 = lane >> 3;

    const unsigned short* xb = xt + (size_t)b * HWSZ * 64;

    // ---------------- Stage window ----------------
    {
        int cc = tid & 7;            // ch chunk
        for (int p = tid >> 3; p < WPX; p += 32) {
            int wy = p / WCOLS, wx = p - wy * WCOLS;
            int iy = y - 2 + wy, ix = x0 - 2 + wx;
            bool v = (iy >= 0) & (iy < HH) & (ix >= 0) & (ix < WW);
            uint4 q = {0, 0, 0, 0};
            if (v) q = *(const uint4*)(xb + (size_t)(iy * WW + ix) * 64 + cc * 8);
            *(uint4*)&win[cc * WSEG + p * 8] = q;
        }
    }
    __syncthreads();

    // ---------------- Phase 1: offset GEMM (B from window, no staging) ----
    {
        int coh = wv & 1;
        int pxh = (wv >> 1) * 32;
        f32x4 oacc[2] = {{0, 0, 0, 0}, {0, 0, 0, 0}};
        for (int k = 0; k < KTAPS; ++k) {
            int ky = k / 3, kx = k - ky * 3;
#pragma unroll
            for (int h = 0; h < 2; ++h) {
                short8 afrag = *(const short8*)(wopk + (size_t)((coh * 18 + k * 2 + h) * 64 + lane) * 8);
                const unsigned short* seg = win + (h * 4 + quad) * WSEG;
#pragma unroll
                for (int pt = 0; pt < 2; ++pt) {
                    int pl = pxh + pt * 16 + n16;
                    int wslot = (ky + 1) * WCOLS + pl + kx + 1;
                    short8 bfrag = *(const short8*)(seg + wslot * 8);
                    oacc[pt] = __builtin_amdgcn_mfma_f32_16x16x32_bf16(afrag, bfrag,
                                                                       oacc[pt], 0, 0, 0);
                }
            }
        }
#pragma unroll
        for (int pt = 0; pt < 2; ++pt) {
#pragma unroll
            for (int r = 0; r < 4; ++r) {
                int co = coh * 16 + quad * 4 + r;
                if (co < 27) omr[co * 64 + pxh + pt * 16 + n16] = oacc[pt][r] + b_off[co];
            }
        }
    }
    __syncthreads();

    // ---------------- Phase 2: bilinear params -> wgt/idx ----------------
    for (int j = tid; j < KTAPS * 64; j += 256) {
        int tap = j >> 6, pl = j & 63;
        int ho = y, wo = x0 + pl;
        float fy = omr[tap * 64 + pl] + (float)(ho - 1 + tap / 3);
        float fx = omr[(9 + tap) * 64 + pl] + (float)(wo - 1 + tap % 3);
        float m = 1.f / (1.f + __expf(-omr[(18 + tap) * 64 + pl]));
        float y0f = floorf(fy), x0f = floorf(fx);
        float dy = fy - y0f, dx = fx - x0f;
        int y0 = (int)y0f, x0i = (int)x0f;
        int y1 = y0 + 1, x1 = x0i + 1;
        bool vy0 = (y0 >= 0) & (y0 < HH);
        bool vy1 = (y1 >= 0) & (y1 < HH);
        bool vx0 = (x0i >= 0) & (x0i < WW);
        bool vx1 = (x1 >= 0) & (x1 < WW);
        float w00 = (1.f - dy) * (1.f - dx) * m; if (!(vy0 && vx0)) w00 = 0.f;
        float w01 = (1.f - dy) * dx * m;         if (!(vy0 && vx1)) w01 = 0.f;
        float w10 = dy * (1.f - dx) * m;         if (!(vy1 && vx0)) w10 = 0.f;
        float w11 = dy * dx * m;                 if (!(vy1 && vx1)) w11 = 0.f;
        int yc0 = min(max(y0, 0), HH - 1), yc1 = min(max(y1, 0), HH - 1);
        int xc0 = min(max(x0i, 0), WW - 1), xc1 = min(max(x1, 0), WW - 1);

        __half2 hA = __floats2half2_rn(w00, w01);
        __half2 hB = __floats2half2_rn(w10, w11);
        wgt[j] = make_uint2(*(unsigned int*)&hA, *(unsigned int*)&hB);

        // window-relative slots; fallback to global idx (bit15) if any OOW
        int uy0 = yc0 - y + 2, uy1 = yc1 - y + 2;
        int ux0 = xc0 - x0 + 2, ux1 = xc1 - x0 + 2;
        bool inw = ((unsigned)uy0 <= 4u) & ((unsigned)uy1 <= 4u) &
                   ((unsigned)ux0 <= 67u) & ((unsigned)ux1 <= 67u);
        if (inw) {
            idxA[j] = make_ushort4((unsigned short)(uy0 * WCOLS + ux0),
                                   (unsigned short)(uy0 * WCOLS + ux1),
                                   (unsigned short)(uy1 * WCOLS + ux0),
                                   (unsigned short)(uy1 * WCOLS + ux1));
        } else {
            idxA[j] = make_ushort4((unsigned short)((yc0 * WW + xc0) | 0x8000),
                                   (unsigned short)(yc0 * WW + xc1),
                                   (unsigned short)(yc1 * WW + xc0),
                                   (unsigned short)(yc1 * WW + xc1));
        }
    }
    __syncthreads();

    // ---------------- Phase 3: main GEMM (1-tap colL rounds) ----------------
    f32x4 acc[4] = {{0, 0, 0, 0}, {0, 0, 0, 0}, {0, 0, 0, 0}, {0, 0, 0, 0}};

    for (int k = 0; k < KTAPS; ++k) {
        // prefetch A-frags (L2-resident; overlaps col build)
        short8 afr0 = *(const short8*)(wpk + (size_t)((wv * 18 + k * 2 + 0) * 64 + lane) * 8);
        short8 afr1 = *(const short8*)(wpk + (size_t)((wv * 18 + k * 2 + 1) * 64 + lane) * 8);

#pragma unroll
        for (int s = 0; s < 2; ++s) {
            int pl = wv * 16 + s * 8 + p8;
            uint2 wp = wgt[k * 64 + pl];
            ushort4 i4 = idxA[k * 64 + pl];
            f32x2 wA = {__low2float(*(__half2*)&wp.x), __high2float(*(__half2*)&wp.x)};
            f32x2 wB = {__low2float(*(__half2*)&wp.y), __high2float(*(__half2*)&wp.y)};

            uint4 qa, qb, qc, qd;
            if (!(i4.x & 0x8000u)) {
                const unsigned short* seg = win + h8 * WSEG;
                qa = *(const uint4*)(seg + i4.x * 8);
                qb = *(const uint4*)(seg + i4.y * 8);
                qc = *(const uint4*)(seg + i4.z * 8);
                qd = *(const uint4*)(seg + i4.w * 8);
            } else {
                qa = *(const uint4*)(xb + (size_t)(i4.x & 0x3fff) * 64 + h8 * 8);
                qb = *(const uint4*)(xb + (size_t)i4.y * 64 + h8 * 8);
                qc = *(const uint4*)(xb + (size_t)i4.z * 64 + h8 * 8);
                qd = *(const uint4*)(xb + (size_t)i4.w * 64 + h8 * 8);
            }
            uint4 r;
            r.x = bilin2(qa.x, qb.x, qc.x, qd.x, wA.x, wA.y, wB.x, wB.y);
            r.y = bilin2(qa.y, qb.y, qc.y, qd.y, wA.x, wA.y, wB.x, wB.y);
            r.z = bilin2(qa.z, qb.z, qc.z, qd.z, wA.x, wA.y, wB.x, wB.y);
            r.w = bilin2(qa.w, qb.w, qc.w, qd.w, wA.x, wA.y, wB.x, wB.y);
            *(uint4*)&colL[pl * LSTR + h8 * 8] = r;
        }
        __syncthreads();

#pragma unroll
        for (int h = 0; h < 2; ++h) {
            short8 afrag = h ? afr1 : afr0;
#pragma unroll
            for (int pt = 0; pt < 4; ++pt) {
                short8 bfrag = *(const short8*)(&colL[(pt * 16 + n16) * LSTR + h * 32 + quad * 8]);
                acc[pt] = __builtin_amdgcn_mfma_f32_16x16x32_bf16(afrag, bfrag,
                                                                  acc[pt], 0, 0, 0);
            }
        }
        __syncthreads();
    }

    // Epilogue: D[m = quad*4+r][n = n16], co = wv*16 + m
    float* ob = out + (size_t)b * COUT * HWSZ;
#pragma unroll
    for (int pt = 0; pt < 4; ++pt) {
        int px = pxbase + pt * 16 + n16;
#pragma unroll
        for (int r = 0; r < 4; ++r) {
            int co = wv * 16 + quad * 4 + r;
            ob[(size_t)co * HWSZ + px] = acc[pt][r] + b_dcn[co];
        }
    }
}

// ---------------------------------------------------------------------------
extern "C" void kernel_launch(void* const* d_in, const int* in_sizes, int n_in,
                              void* d_out, int out_size, void* d_ws, size_t ws_size,
                              hipStream_t stream) {
    const float* x     = (const float*)d_in[0];
    const float* w_off = (const float*)d_in[1];
    const float* b_off = (const float*)d_in[2];
    const float* w_dcn = (const float*)d_in[3];
    const float* b_dcn = (const float*)d_in[4];
    float* out = (float*)d_out;

    // ws layout: xt (bf16 NHWC, 16 MB) | wpk | wopk
    unsigned short* xt   = (unsigned short*)d_ws;
    unsigned short* wpk  = xt + (size_t)BATCH * HWSZ * 64;   // 36864
    unsigned short* wopk = wpk + 36864;                      // 18432

    hipLaunchKernelGGL(transpose_x_kernel, dim3(2048), dim3(256), 0, stream,
                       x, xt, w_dcn, w_off, wpk, wopk);
    hipLaunchKernelGGL(dcn_fused_mfma, dim3(BATCH * HWSZ / 64), dim3(256),
                       0, stream, xt, wpk, wopk, b_off, b_dcn, out);
}

// Round 9
// 136.616 us; speedup vs baseline: 1.1254x; 1.1254x over previous
//
#include <hip/hip_runtime.h>
#include <math.h>

#define BATCH 8
#define CH    64
#define HH    128
#define WW    128
#define HWSZ  (HH * WW)       // 16384
#define COUT  64
#define KTAPS 9
#define KDIM  576             // CH * KTAPS
#define LSTR  72              // ushorts per colL px-row (144 B)
#define TROWS 6               // window rows: y-2 .. y+3
#define TCOLS 36              // window cols: x0-2 .. x0+33
#define TSLOTS 216            // 6 * 36
#define WSEGU 1736            // ushorts per ch-segment (216*8=1728, +8 pad:
                              // 868 dw ≡ 4 mod 32 -> 8 segs on 8 bank phases)

typedef __attribute__((ext_vector_type(8))) short short8;
typedef __attribute__((ext_vector_type(4))) float f32x4;
typedef __attribute__((ext_vector_type(2))) float f32x2;

__device__ __forceinline__ unsigned short f2bf(float f) {
    unsigned int u = __float_as_uint(f);
    u += 0x7fffu + ((u >> 16) & 1u);
    return (unsigned short)(u >> 16);
}
__device__ __forceinline__ f32x2 up2(unsigned int u) {
    f32x2 r;
    r.x = __uint_as_float(u << 16);
    r.y = __uint_as_float(u & 0xffff0000u);
    return r;
}
__device__ __forceinline__ unsigned int bilin2(unsigned int a, unsigned int b,
                                               unsigned int c, unsigned int d,
                                               float w00, float w01, float w10, float w11) {
    f32x2 acc = up2(a) * w00;
    acc = up2(b) * w01 + acc;
    acc = up2(c) * w10 + acc;
    acc = up2(d) * w11 + acc;
    return __builtin_amdgcn_perm(__float_as_uint(acc.y) + 0x8000u,
                                 __float_as_uint(acc.x) + 0x8000u, 0x07060302u);
}

// ---------------------------------------------------------------------------
// Kernel 0: repack conv weights into wave-contiguous A-fragment layouts.
//  wpk [mt<4][ks<18][lane<64][8]: lane(n16,quad) holds
//      w_dcn[co=mt*16+n16][c=(ks&1)*32+quad*8+j], tap=ks>>1
//  wopk[cot<2][ks<18][lane<64][8]: same for w_off (co>=27 zeroed)
// ---------------------------------------------------------------------------
__global__ __launch_bounds__(256) void prep_w_kernel(
    const float* __restrict__ w_dcn, const float* __restrict__ w_off,
    unsigned short* __restrict__ wpk, unsigned short* __restrict__ wopk) {
    int j = blockIdx.x * 256 + threadIdx.x;
    if (j < 36864) {
        int jj = j & 7, ln = (j >> 3) & 63, q = j >> 9;   // q: 0..71
        int ks = q % 18, mt = q / 18;
        int tap = ks >> 1, h = ks & 1;
        int co = mt * 16 + (ln & 15);
        int c  = h * 32 + (ln >> 4) * 8 + jj;
        wpk[j] = f2bf(w_dcn[(co * CH + c) * KTAPS + tap]);
    } else if (j < 55296) {
        int jo = j - 36864;
        int jj = jo & 7, ln = (jo >> 3) & 63, q = jo >> 9; // q: 0..35
        int ks = q % 18, cot = q / 18;
        int tap = ks >> 1, h = ks & 1;
        int co = cot * 16 + (ln & 15);
        int c  = h * 32 + (ln >> 4) * 8 + jj;
        wopk[jo] = (co < 27) ? f2bf(w_off[(co * CH + c) * KTAPS + tap]) : 0;
    }
}

// ---------------------------------------------------------------------------
// Kernel 1: SINGLE FUSED DCN. Block tile = 2 rows x 32 cols (64 px).
//  Stage: win[c8][216 slots][8ch] bf16 <- 6x36 neighborhood straight from
//         NCHW fp32 x (zero-padded OOB). Bank-clean (WSEGU pad).
//  Phase 1: offset GEMM 32co x 64px, B-frags ds_read_b128 from window.
//  Phase 2: bilinear params -> wgt float4 + idx uint (window slot, corners at
//           s,s+1,s+36,s+37; bit31 -> packed clamped coords, global fallback).
//  Phase 3: per tap: col build (corners from window) -> colL -> MFMA 64co x 64px.
// LDS: win 27776 | colL 9216 (union omr 6912) | wgt 9216 | idx 2304 = 48512 B
//      -> 3 blocks/CU.
// ---------------------------------------------------------------------------
__global__ __launch_bounds__(256) void dcn_fused_mfma(
    const float* __restrict__ x, const unsigned short* __restrict__ wpk,
    const unsigned short* __restrict__ wopk, const float* __restrict__ b_off,
    const float* __restrict__ b_dcn, float* __restrict__ out) {
    __shared__ __align__(16) unsigned char smem[48512];
    unsigned short* win = (unsigned short*)smem;           // [8][WSEGU]
    unsigned short* colL = (unsigned short*)(smem + 27776);
    float* omr = (float*)(smem + 27776);                   // union w/ colL
    float4* wgt = (float4*)(smem + 36992);                 // [9][64]
    unsigned int* idxU = (unsigned int*)(smem + 46208);    // [9][64]

    int tid = threadIdx.x, bid = blockIdx.x;
    int b = bid & 7;                 // batch -> XCD pinning
    int T = bid >> 3;                // tile 0..255 per image
    int y = (T >> 2) * 2;            // tile row base (2 rows)
    int x0 = (T & 3) * 32;           // tile col base
    int lane = tid & 63, wv = tid >> 6;
    int quad = lane >> 4, n16 = lane & 15;
    int h8 = lane & 7, p8 = lane >> 3;

    const float* xbf = x + (size_t)b * CH * HWSZ;

    // ---------------- Stage window from NCHW fp32 ----------------
    for (int p = tid; p < 8 * TSLOTS; p += 256) {
        int c8 = p / TSLOTS, slot = p - c8 * TSLOTS;
        int wy = slot / TCOLS, wx = slot - wy * TCOLS;
        int iy = y - 2 + wy, ix = x0 - 2 + wx;
        bool v = (iy >= 0) & (iy < HH) & (ix >= 0) & (ix < WW);
        uint4 q = {0, 0, 0, 0};
        if (v) {
            const float* pc0 = xbf + (size_t)(c8 * 8) * HWSZ + iy * WW + ix;
            unsigned int u0 = f2bf(pc0[0]);
            unsigned int u1 = f2bf(pc0[HWSZ]);
            unsigned int u2 = f2bf(pc0[2 * HWSZ]);
            unsigned int u3 = f2bf(pc0[3 * HWSZ]);
            unsigned int u4 = f2bf(pc0[4 * HWSZ]);
            unsigned int u5 = f2bf(pc0[5 * HWSZ]);
            unsigned int u6 = f2bf(pc0[6 * HWSZ]);
            unsigned int u7 = f2bf(pc0[7 * HWSZ]);
            q.x = u0 | (u1 << 16);
            q.y = u2 | (u3 << 16);
            q.z = u4 | (u5 << 16);
            q.w = u6 | (u7 << 16);
        }
        *(uint4*)&win[c8 * WSEGU + slot * 8] = q;
    }
    __syncthreads();

    // ---------------- Phase 1: offset GEMM (B from window) ----------------
    {
        int coh = wv & 1;
        int pxh = (wv >> 1) * 32;
        int prw = wv >> 1;               // this wave's px row within tile
        f32x4 oacc[2] = {{0, 0, 0, 0}, {0, 0, 0, 0}};
        for (int k = 0; k < KTAPS; ++k) {
            int ky = k / 3, kx = k - ky * 3;
#pragma unroll
            for (int h = 0; h < 2; ++h) {
                short8 afrag = *(const short8*)(wopk + (size_t)((coh * 18 + k * 2 + h) * 64 + lane) * 8);
                const unsigned short* seg = win + (h * 4 + quad) * WSEGU;
#pragma unroll
                for (int pt = 0; pt < 2; ++pt) {
                    int pc = pt * 16 + n16;
                    int slot = (prw + ky + 1) * TCOLS + pc + kx + 1;
                    short8 bfrag = *(const short8*)(seg + slot * 8);
                    oacc[pt] = __builtin_amdgcn_mfma_f32_16x16x32_bf16(afrag, bfrag,
                                                                       oacc[pt], 0, 0, 0);
                }
            }
        }
#pragma unroll
        for (int pt = 0; pt < 2; ++pt) {
#pragma unroll
            for (int r = 0; r < 4; ++r) {
                int co = coh * 16 + quad * 4 + r;
                if (co < 27) omr[co * 64 + pxh + pt * 16 + n16] = oacc[pt][r] + b_off[co];
            }
        }
    }
    __syncthreads();

    // ---------------- Phase 2: bilinear params -> wgt/idx ----------------
    for (int j = tid; j < KTAPS * 64; j += 256) {
        int tap = j >> 6, pl = j & 63;
        int pr = pl >> 5, pc = pl & 31;
        int ho = y + pr, wo = x0 + pc;
        float fy = omr[tap * 64 + pl] + (float)(ho - 1 + tap / 3);
        float fx = omr[(9 + tap) * 64 + pl] + (float)(wo - 1 + tap % 3);
        float m = 1.f / (1.f + __expf(-omr[(18 + tap) * 64 + pl]));
        float y0f = floorf(fy), x0f = floorf(fx);
        float dy = fy - y0f, dx = fx - x0f;
        int y0 = (int)y0f, x0i = (int)x0f;
        int y1 = y0 + 1, x1 = x0i + 1;
        bool vy0 = (y0 >= 0) & (y0 < HH);
        bool vy1 = (y1 >= 0) & (y1 < HH);
        bool vx0 = (x0i >= 0) & (x0i < WW);
        bool vx1 = (x1 >= 0) & (x1 < WW);
        float w00 = (1.f - dy) * (1.f - dx) * m; if (!(vy0 && vx0)) w00 = 0.f;
        float w01 = (1.f - dy) * dx * m;         if (!(vy0 && vx1)) w01 = 0.f;
        float w10 = dy * (1.f - dx) * m;         if (!(vy1 && vx0)) w10 = 0.f;
        float w11 = dy * dx * m;                 if (!(vy1 && vx1)) w11 = 0.f;
        int yc0 = min(max(y0, 0), HH - 1), yc1 = min(max(y1, 0), HH - 1);
        int xc0 = min(max(x0i, 0), WW - 1), xc1 = min(max(x1, 0), WW - 1);
        wgt[j] = make_float4(w00, w01, w10, w11);

        // window slot (unclamped base); corners s, s+1, s+36, s+37
        int uy = y0 - (y - 2), ux = x0i - (x0 - 2);
        bool inw = ((unsigned)uy <= 4u) & ((unsigned)ux <= 34u);
        unsigned int enc;
        if (inw) enc = (unsigned)(uy * TCOLS + ux);
        else     enc = 0x80000000u | ((unsigned)yc0 << 21) | ((unsigned)xc0 << 14)
                                   | ((unsigned)yc1 << 7)  | (unsigned)xc1;
        idxU[j] = enc;
    }
    __syncthreads();

    // ---------------- Phase 3: main GEMM (1-tap colL rounds) ----------------
    f32x4 acc[4] = {{0, 0, 0, 0}, {0, 0, 0, 0}, {0, 0, 0, 0}, {0, 0, 0, 0}};

    for (int k = 0; k < KTAPS; ++k) {
        short8 afr0 = *(const short8*)(wpk + (size_t)((wv * 18 + k * 2 + 0) * 64 + lane) * 8);
        short8 afr1 = *(const short8*)(wpk + (size_t)((wv * 18 + k * 2 + 1) * 64 + lane) * 8);

#pragma unroll
        for (int s = 0; s < 2; ++s) {
            int pl = wv * 16 + s * 8 + p8;
            float4 w4 = wgt[k * 64 + pl];
            unsigned int iu = idxU[k * 64 + pl];
            uint4 qa, qb, qc, qd;
            if (__builtin_expect(!(iu & 0x80000000u), 1)) {
                const unsigned short* base = win + h8 * WSEGU + iu * 8;
                qa = *(const uint4*)(base);
                qb = *(const uint4*)(base + 8);
                qc = *(const uint4*)(base + TCOLS * 8);
                qd = *(const uint4*)(base + TCOLS * 8 + 8);
            } else {
                int yc0 = (iu >> 21) & 0x7f, xc0 = (iu >> 14) & 0x7f;
                int yc1 = (iu >> 7) & 0x7f,  xc1 = iu & 0x7f;
                const float* pc0 = xbf + (size_t)(h8 * 8) * HWSZ;
                auto ld8 = [&](int yy, int xx) {
                    const float* p = pc0 + yy * WW + xx;
                    unsigned int u0 = f2bf(p[0]),        u1 = f2bf(p[HWSZ]);
                    unsigned int u2 = f2bf(p[2 * HWSZ]), u3 = f2bf(p[3 * HWSZ]);
                    unsigned int u4 = f2bf(p[4 * HWSZ]), u5 = f2bf(p[5 * HWSZ]);
                    unsigned int u6 = f2bf(p[6 * HWSZ]), u7 = f2bf(p[7 * HWSZ]);
                    uint4 q;
                    q.x = u0 | (u1 << 16); q.y = u2 | (u3 << 16);
                    q.z = u4 | (u5 << 16); q.w = u6 | (u7 << 16);
                    return q;
                };
                qa = ld8(yc0, xc0); qb = ld8(yc0, xc1);
                qc = ld8(yc1, xc0); qd = ld8(yc1, xc1);
            }
            uint4 r;
            r.x = bilin2(qa.x, qb.x, qc.x, qd.x, w4.x, w4.y, w4.z, w4.w);
            r.y = bilin2(qa.y, qb.y, qc.y, qd.y, w4.x, w4.y, w4.z, w4.w);
            r.z = bilin2(qa.z, qb.z, qc.z, qd.z, w4.x, w4.y, w4.z, w4.w);
            r.w = bilin2(qa.w, qb.w, qc.w, qd.w, w4.x, w4.y, w4.z, w4.w);
            *(uint4*)&colL[pl * LSTR + h8 * 8] = r;
        }
        __syncthreads();

#pragma unroll
        for (int h = 0; h < 2; ++h) {
            short8 afrag = h ? afr1 : afr0;
#pragma unroll
            for (int pt = 0; pt < 4; ++pt) {
                short8 bfrag = *(const short8*)(&colL[(pt * 16 + n16) * LSTR + h * 32 + quad * 8]);
                acc[pt] = __builtin_amdgcn_mfma_f32_16x16x32_bf16(afrag, bfrag,
                                                                  acc[pt], 0, 0, 0);
            }
        }
        __syncthreads();
    }

    // Epilogue: D[m=quad*4+r][n=n16], co = wv*16 + m; px = pt*16+n16 -> (pr,pc)
    float* ob = out + (size_t)b * COUT * HWSZ;
#pragma unroll
    for (int pt = 0; pt < 4; ++pt) {
        int px = pt * 16 + n16;
        int gidx = (y + (px >> 5)) * WW + x0 + (px & 31);
#pragma unroll
        for (int r = 0; r < 4; ++r) {
            int co = wv * 16 + quad * 4 + r;
            ob[(size_t)co * HWSZ + gidx] = acc[pt][r] + b_dcn[co];
        }
    }
}

// ---------------------------------------------------------------------------
extern "C" void kernel_launch(void* const* d_in, const int* in_sizes, int n_in,
                              void* d_out, int out_size, void* d_ws, size_t ws_size,
                              hipStream_t stream) {
    const float* x     = (const float*)d_in[0];
    const float* w_off = (const float*)d_in[1];
    const float* b_off = (const float*)d_in[2];
    const float* w_dcn = (const float*)d_in[3];
    const float* b_dcn = (const float*)d_in[4];
    float* out = (float*)d_out;

    // ws layout: wpk | wopk (bf16 repacked weights only)
    unsigned short* wpk  = (unsigned short*)d_ws;            // 36864
    unsigned short* wopk = wpk + 36864;                      // 18432

    hipLaunchKernelGGL(prep_w_kernel, dim3(216), dim3(256), 0, stream,
                       w_dcn, w_off, wpk, wopk);
    hipLaunchKernelGGL(dcn_fused_mfma, dim3(BATCH * HWSZ / 64), dim3(256),
                       0, stream, x, wpk, wopk, b_off, b_dcn, out);
}